// Round 1
// baseline (1601.093 us; speedup 1.0000x reference)
//
#include <hip/hip_runtime.h>
#include <math.h>

#define NB 8
#define NL 4096
#define NDIM 512
#define NS 32
#define NTOP 8
#define FEPS 1e-8f
#define NM (NB*NL)   // 32768 tokens

// ---------------- K1: phase + avg magnitude per token ----------------
__global__ __launch_bounds__(256) void k_phase(
    const float4* __restrict__ z4, const float2* __restrict__ wr2,
    const float2* __restrict__ wi2, float* __restrict__ phase,
    float* __restrict__ avgmag) {
  int lane = threadIdx.x & 63;
  int m = blockIdx.x * 4 + (threadIdx.x >> 6);
  const float4* row = z4 + (size_t)m * 256;   // 256 float4 per token row
  float pr = 0.f, pi = 0.f, ms = 0.f;
#pragma unroll
  for (int j = 0; j < 4; j++) {
    int idx = lane + 64 * j;                  // covers d = 2*idx, 2*idx+1
    float4 v = row[idx];
    float2 wr = wr2[idx], wi = wi2[idx];
    pr += v.x * wr.x - v.y * wi.x + v.z * wr.y - v.w * wi.y;
    pi += v.x * wi.x + v.y * wr.x + v.z * wi.y + v.w * wr.y;
    ms += sqrtf(v.x * v.x + v.y * v.y + FEPS) + sqrtf(v.z * v.z + v.w * v.w + FEPS);
  }
#pragma unroll
  for (int off = 32; off >= 1; off >>= 1) {
    pr += __shfl_xor(pr, off);
    pi += __shfl_xor(pi, off);
    ms += __shfl_xor(ms, off);
  }
  if (lane == 0) {
    phase[m] = sqrtf(pr * pr + pi * pi + FEPS);
    avgmag[m] = ms * (1.0f / 512.0f);
  }
}

// ---------------- K2: salience + run scan (one block per batch row) ----------------
__global__ __launch_bounds__(256) void k_scan(
    const float* __restrict__ phase, const float* __restrict__ avgmag,
    const float* __restrict__ bias_p, const float* __restrict__ ns_p,
    float* __restrict__ salO, int* __restrict__ estart, int* __restrict__ eend) {
  __shared__ float am[NL];
  __shared__ int abv[NL];
  __shared__ int cnt[256];
  int b = blockIdx.x, t = threadIdx.x;
  size_t gb = (size_t)b * NL;
  if (t < NS) { estart[b * NS + t] = -1; eend[b * NS + t] = -1; }
  for (int i = t; i < NL; i += 256) am[i] = avgmag[gb + i];
  __syncthreads();
  float bias = bias_p[0], ns = ns_p[0];
  for (int i = t; i < NL; i += 256) {
    float lm = am[i];
    if (i >= 2) lm += am[i - 2];
    if (i >= 1) lm += am[i - 1];
    if (i <= NL - 2) lm += am[i + 1];
    if (i <= NL - 3) lm += am[i + 2];
    lm *= 0.2f;
    float x = phase[gb + i] + (am[i] - lm) * ns + bias;
    float s = 1.0f / (1.0f + expf(-x));
    salO[gb + i] = s;
    abv[i] = (s > 0.5f) ? 1 : 0;
  }
  __syncthreads();
  // count starts in each thread's 16-token chunk
  int c = 0, l0 = t * 16;
  for (int j = 0; j < 16; j++) {
    int l = l0 + j;
    int a = abv[l];
    int p = (l == 0) ? 0 : abv[l - 1];
    c += (a && !p) ? 1 : 0;
  }
  cnt[t] = c;
  __syncthreads();
  for (int off = 1; off < 256; off <<= 1) {   // inclusive Hillis-Steele scan
    int v = (t >= off) ? cnt[t - off] : 0;
    __syncthreads();
    cnt[t] += v;
    __syncthreads();
  }
  c = (t > 0) ? cnt[t - 1] : 0;
  for (int j = 0; j < 16; j++) {
    int l = l0 + j;
    int a = abv[l];
    int p = (l == 0) ? 0 : abv[l - 1];
    int st = (a && !p) ? 1 : 0;
    c += st;
    int ev = c - 1;
    if (a && ev >= 0 && ev < NS) {
      if (st) estart[b * NS + ev] = l;
      int nxt = (l == NL - 1) ? 0 : abv[l + 1];
      if (!nxt) eend[b * NS + ev] = l + 1;
    }
  }
}

// ---------------- K3: event accumulation (one block per (b,s)) ----------------
__global__ __launch_bounds__(256) void k_event(
    const float4* __restrict__ z4, const float* __restrict__ salO,
    const int* __restrict__ estart, const int* __restrict__ eend,
    float4* __restrict__ evec4, float* __restrict__ emask) {
  int i = blockIdx.x;            // b*NS + s
  int b = i >> 5;
  int t = threadIdx.x;
  int st = estart[i];
  int en = (st >= 0) ? eend[i] : 0;
  if (st < 0) st = 0;
  float4 acc = {0.f, 0.f, 0.f, 0.f};
  float den = 0.f;
  for (int l = st; l < en; l++) {
    float w = salO[(size_t)b * NL + l];
    float4 v = z4[((size_t)b * NL + l) * 256 + t];
    acc.x += w * v.x; acc.y += w * v.y; acc.z += w * v.z; acc.w += w * v.w;
    den += w;
  }
  float inv = 1.0f / fmaxf(den, FEPS);
  float4 o = {acc.x * inv, acc.y * inv, acc.z * inv, acc.w * inv};
  evec4[(size_t)i * 256 + t] = o;
  if (t == 0) emask[i] = (den > 0.f) ? 1.0f : 0.0f;
}

// ---------------- K4: event keys/values + blend + kmag + new_mask ----------------
__global__ __launch_bounds__(256) void k_kv(
    const float* __restrict__ evec, const float* __restrict__ emask,
    const float* __restrict__ Wekr, const float* __restrict__ Weki,
    const float* __restrict__ Wevr, const float* __restrict__ Wevi,
    const float* __restrict__ slotK, const float* __restrict__ slotV,
    const float* __restrict__ slotM, float* __restrict__ newK,
    float* __restrict__ newV, float* __restrict__ newM,
    float* __restrict__ kmag) {
  __shared__ float ev[1024];
  __shared__ float red[256];
  int i = blockIdx.x, t = threadIdx.x;
  for (int j = t; j < 1024; j += 256) ev[j] = evec[(size_t)i * 1024 + j];
  __syncthreads();
  int d0 = t, d1 = t + 256;
  float kr0 = 0, ki0 = 0, kr1 = 0, ki1 = 0;
  float vr0 = 0, vi0 = 0, vr1 = 0, vi1 = 0;
  for (int k = 0; k < NDIM; k++) {
    float er = ev[2 * k], ei = ev[2 * k + 1];
    int o = k * NDIM;
    float a0 = Wekr[o + d0], a1 = Wekr[o + d1];
    float b0 = Weki[o + d0], b1 = Weki[o + d1];
    kr0 += er * a0 - ei * b0; ki0 += er * b0 + ei * a0;
    kr1 += er * a1 - ei * b1; ki1 += er * b1 + ei * a1;
    a0 = Wevr[o + d0]; a1 = Wevr[o + d1];
    b0 = Wevi[o + d0]; b1 = Wevi[o + d1];
    vr0 += er * a0 - ei * b0; vi0 += er * b0 + ei * a0;
    vr1 += er * a1 - ei * b1; vi1 += er * b1 + ei * a1;
  }
  float m = emask[i];
  const float2* sk = (const float2*)slotK + (size_t)i * NDIM;
  const float2* sv = (const float2*)slotV + (size_t)i * NDIM;
  float2 s0 = sk[d0], s1 = sk[d1], t0 = sv[d0], t1 = sv[d1];
  float nkr0 = (m > 0.f) ? kr0 : s0.x, nki0 = (m > 0.f) ? ki0 : s0.y;
  float nkr1 = (m > 0.f) ? kr1 : s1.x, nki1 = (m > 0.f) ? ki1 : s1.y;
  float nvr0 = (m > 0.f) ? vr0 : t0.x, nvi0 = (m > 0.f) ? vi0 : t0.y;
  float nvr1 = (m > 0.f) ? vr1 : t1.x, nvi1 = (m > 0.f) ? vi1 : t1.y;
  float2* nk = (float2*)newK + (size_t)i * NDIM;
  float2* nv = (float2*)newV + (size_t)i * NDIM;
  nk[d0] = {nkr0, nki0}; nk[d1] = {nkr1, nki1};
  nv[d0] = {nvr0, nvi0}; nv[d1] = {nvr1, nvi1};
  red[t] = nkr0 * nkr0 + nki0 * nki0 + nkr1 * nkr1 + nki1 * nki1;
  __syncthreads();
  for (int off = 128; off >= 1; off >>= 1) {
    if (t < off) red[t] += red[t + off];
    __syncthreads();
  }
  if (t == 0) {
    kmag[i] = sqrtf(red[0] + FEPS);
    newM[i] = fminf(slotM[i] + m, 1.0f);
  }
}

// ---------------- K5: Q = Zc @ Bcomp  (fp32 SGEMM, composite complex) ----------------
// A (M x 1024): cols 0..511 = zr, 512..1023 = zi  (read from interleaved z)
// B (1024 x 1024): [[Wr, Wi], [-Wi, Wr]] built on the fly from W_rq_r / W_rq_i
__global__ __launch_bounds__(256) void k_gemm(
    const float2* __restrict__ z2, const float* __restrict__ Wr,
    const float* __restrict__ Wi, float* __restrict__ Q) {
  __shared__ __align__(16) float As[16][132];
  __shared__ __align__(16) float Bs[16][128];
  int t = threadIdx.x;
  int n0 = blockIdx.x * 128;
  int m0 = blockIdx.y * 128;
  int tx = t & 15, ty = t >> 4;
  int mloc = t >> 1, kc = (t & 1) * 8;   // A staging: 128 rows x 2 k-chunks
  int kb = t >> 4, nc = (t & 15) * 8;    // B staging: 16 k x 16 n-chunks
  float acc[8][8];
#pragma unroll
  for (int i = 0; i < 8; i++)
#pragma unroll
    for (int j = 0; j < 8; j++) acc[i][j] = 0.f;

  for (int kt = 0; kt < 1024; kt += 16) {
    {  // stage A
      int gk = kt + kc;
      int half = (gk >= 512) ? 1 : 0;
      int dd = gk - half * 512;
      const float2* src = z2 + (size_t)(m0 + mloc) * NDIM + dd;
#pragma unroll
      for (int j = 0; j < 8; j++) {
        float2 v = src[j];
        As[kc + j][mloc] = half ? v.y : v.x;
      }
    }
    {  // stage B
      int gk = kt + kb;
      int gn = n0 + nc;
      const float* src;
      float sgn = 1.0f;
      if (gk < 512) {
        src = (gn < 512) ? (Wr + gk * 512 + gn) : (Wi + gk * 512 + (gn - 512));
      } else {
        if (gn < 512) { src = Wi + (gk - 512) * 512 + gn; sgn = -1.0f; }
        else          { src = Wr + (gk - 512) * 512 + (gn - 512); }
      }
      float4 b0 = *(const float4*)src;
      float4 b1 = *(const float4*)(src + 4);
      Bs[kb][nc + 0] = sgn * b0.x; Bs[kb][nc + 1] = sgn * b0.y;
      Bs[kb][nc + 2] = sgn * b0.z; Bs[kb][nc + 3] = sgn * b0.w;
      Bs[kb][nc + 4] = sgn * b1.x; Bs[kb][nc + 5] = sgn * b1.y;
      Bs[kb][nc + 6] = sgn * b1.z; Bs[kb][nc + 7] = sgn * b1.w;
    }
    __syncthreads();
#pragma unroll
    for (int k = 0; k < 16; k++) {
      float4 a0 = *(const float4*)&As[k][ty * 8];
      float4 a1 = *(const float4*)&As[k][ty * 8 + 4];
      float4 b0 = *(const float4*)&Bs[k][tx * 8];
      float4 b1 = *(const float4*)&Bs[k][tx * 8 + 4];
      float a[8] = {a0.x, a0.y, a0.z, a0.w, a1.x, a1.y, a1.z, a1.w};
      float bb[8] = {b0.x, b0.y, b0.z, b0.w, b1.x, b1.y, b1.z, b1.w};
#pragma unroll
      for (int i = 0; i < 8; i++)
#pragma unroll
        for (int j = 0; j < 8; j++) acc[i][j] += a[i] * bb[j];
    }
    __syncthreads();
  }
#pragma unroll
  for (int i = 0; i < 8; i++) {
    float* dst = Q + (size_t)(m0 + ty * 8 + i) * 1024 + n0 + tx * 8;
    float4 o0 = {acc[i][0], acc[i][1], acc[i][2], acc[i][3]};
    float4 o1 = {acc[i][4], acc[i][5], acc[i][6], acc[i][7]};
    *(float4*)dst = o0;
    *(float4*)(dst + 4) = o1;
  }
}

// ---------------- K6: attention tail, one wave per token ----------------
__global__ __launch_bounds__(256) void k_attn(
    const float* __restrict__ Q, const float* __restrict__ newK,
    const float* __restrict__ newV, const float* __restrict__ newM,
    const float* __restrict__ kmag, const float* __restrict__ gain,
    float* __restrict__ out0) {
  int lane = threadIdx.x & 63;
  int m = blockIdx.x * 4 + (threadIdx.x >> 6);
  int b = m >> 12;
  const float* qrow = Q + (size_t)m * 1024;
  float qr[8], qi[8];
  float qm2 = 0.f;
#pragma unroll
  for (int j = 0; j < 8; j++) {
    int d = lane + 64 * j;
    qr[j] = qrow[d];
    qi[j] = qrow[512 + d];
    qm2 += qr[j] * qr[j] + qi[j] * qi[j];
  }
#pragma unroll
  for (int off = 32; off >= 1; off >>= 1) qm2 += __shfl_xor(qm2, off);
  float qmag = sqrtf(qm2 + FEPS);

  const float2* K2p = (const float2*)newK + (size_t)b * NS * NDIM;
  float myscore = -3.0e38f;
  for (int s = 0; s < NS; s++) {
    const float2* krow = K2p + (size_t)s * NDIM;
    float p = 0.f;
#pragma unroll
    for (int j = 0; j < 8; j++) {
      int d = lane + 64 * j;
      float2 kv = krow[d];
      p += qr[j] * kv.x + qi[j] * kv.y;
    }
#pragma unroll
    for (int off = 32; off >= 1; off >>= 1) p += __shfl_xor(p, off);
    float km = kmag[b * NS + s];
    float sc = p / (qmag * km + FEPS);
    if (newM[b * NS + s] == 0.0f) sc = -1.0e9f;
    if ((lane & 31) == s) myscore = sc;
  }

  // top-8, stable (lower index wins ties), like lax.top_k
  float topv[NTOP];
  int topi[NTOP];
#pragma unroll
  for (int it = 0; it < NTOP; it++) {
    float val = myscore;
    int idx = lane & 31;
#pragma unroll
    for (int off = 32; off >= 1; off >>= 1) {
      float ov = __shfl_xor(val, off);
      int oi = __shfl_xor(idx, off);
      if (ov > val || (ov == val && oi < idx)) { val = ov; idx = oi; }
    }
    topv[it] = val;
    topi[it] = idx;
    if ((lane & 31) == idx) myscore = -3.0e38f;
  }
  float mx = topv[0];
  float w[NTOP], wsum = 0.f;
#pragma unroll
  for (int it = 0; it < NTOP; it++) { w[it] = expf(topv[it] - mx); wsum += w[it]; }
  float inv = 1.0f / wsum;

  const float2* V2p = (const float2*)newV + (size_t)b * NS * NDIM;
  float vr[8], vi[8];
#pragma unroll
  for (int j = 0; j < 8; j++) { vr[j] = 0.f; vi[j] = 0.f; }
#pragma unroll
  for (int it = 0; it < NTOP; it++) {
    float a = w[it] * inv;
    const float2* vrow = V2p + (size_t)topi[it] * NDIM;
#pragma unroll
    for (int j = 0; j < 8; j++) {
      float2 v = vrow[lane + 64 * j];
      vr[j] += a * v.x;
      vi[j] += a * v.y;
    }
  }
  float r2 = 0.f;
#pragma unroll
  for (int j = 0; j < 8; j++) r2 += vr[j] * vr[j] + vi[j] * vi[j];
#pragma unroll
  for (int off = 32; off >= 1; off >>= 1) r2 += __shfl_xor(r2, off);
  float rinv = 1.0f / sqrtf(r2 * (1.0f / 512.0f) + FEPS);

  float2* orow = (float2*)out0 + (size_t)m * NDIM;
#pragma unroll
  for (int j = 0; j < 8; j++) {
    int d = lane + 64 * j;
    float g = gain[d] * rinv;
    orow[d] = {vr[j] * g, vi[j] * g};
  }
}

extern "C" void kernel_launch(void* const* d_in, const int* in_sizes, int n_in,
                              void* d_out, int out_size, void* d_ws, size_t ws_size,
                              hipStream_t stream) {
  const float* z      = (const float*)d_in[0];
  const float* slotK  = (const float*)d_in[1];
  const float* slotV  = (const float*)d_in[2];
  const float* slotM  = (const float*)d_in[3];
  const float* Wsr    = (const float*)d_in[4];
  const float* Wsi    = (const float*)d_in[5];
  const float* sbias  = (const float*)d_in[6];
  const float* nscale = (const float*)d_in[7];
  const float* Wekr   = (const float*)d_in[8];
  const float* Weki   = (const float*)d_in[9];
  const float* Wevr   = (const float*)d_in[10];
  const float* Wevi   = (const float*)d_in[11];
  const float* Wrqr   = (const float*)d_in[12];
  const float* Wrqi   = (const float*)d_in[13];
  const float* gain   = (const float*)d_in[14];

  float* out = (float*)d_out;
  float* out0 = out;                       // (B,L,DIM,2)
  float* newK = out + 33554432;            // (B,S,DIM,2)
  float* newV = newK + 262144;
  float* newM = newV + 262144;             // (B,S)
  float* salO = newM + 256;                // (B,L)

  float* ws = (float*)d_ws;
  float* Q      = ws;                      // (M,1024) = 128 MB
  float* phaseb = ws + 33554432;
  float* avgmgb = phaseb + NM;
  float* evec   = avgmgb + NM;             // (B*S,1024)
  float* emask  = evec + NB * NS * 1024;
  float* kmagb  = emask + NB * NS;
  int* estart   = (int*)(kmagb + NB * NS);
  int* eend     = estart + NB * NS;

  k_phase<<<NM / 4, 256, 0, stream>>>((const float4*)z, (const float2*)Wsr,
                                      (const float2*)Wsi, phaseb, avgmgb);
  k_scan<<<NB, 256, 0, stream>>>(phaseb, avgmgb, sbias, nscale, salO, estart, eend);
  k_event<<<NB * NS, 256, 0, stream>>>((const float4*)z, salO, estart, eend,
                                       (float4*)evec, emask);
  k_kv<<<NB * NS, 256, 0, stream>>>(evec, emask, Wekr, Weki, Wevr, Wevi,
                                    slotK, slotV, slotM, newK, newV, newM, kmagb);
  dim3 g5(8, NM / 128);
  k_gemm<<<g5, 256, 0, stream>>>((const float2*)z, Wrqr, Wrqi, Q);
  k_attn<<<NM / 4, 256, 0, stream>>>(Q, newK, newV, newM, kmagb, gain, out0);
}